// Round 11
// baseline (376.989 us; speedup 1.0000x reference)
//
#include <hip/hip_runtime.h>
#include <math.h>

// EnvAwareRouter: B=524288, C=13, T=24, H=64, E=8, K=3, tau=1, eps=1e-10
// Output: concat[ mask(B,E), probs(B,E) ] f32
//
// R11 = R10 with the register footprint cut (occupancy was the binding
// constraint: ~38% = 3 waves/SIMD in R8-R10 regardless of block shape;
// VGPR_Count=60 excludes the unified-file AGPR side where Bf[3][4] (48 regs)
// + accumulators live).
//  - B-operand (tw1 bf16x3 fragments) moved to LDS (12 KB), built once per
//    block; per-tile per-ct 3x ds_read_b128 with per-lane addresses.
//    Frees 48 VGPRs per wave.
//  - software-pipelined x loads (prefetch si+1 under si's gelu block).
//  - #pragma unroll 2 on the gumbel loop (8 parallel fp64 fast_log chains
//    were a phase-2 register spike).
//  - numerics verbatim R10 (validated: absmax 0.0039, zero top-3 flips):
//    3-split bf16 MFMA w/ 6 products, A&S erf gelu, custom fp64 gumbel log,
//    fp64 y ordering, fp32 softmax.

constexpr int Bn = 524288, Cn = 13, Tn = 24, Hn = 64, En = 8, Kn = 3;
constexpr int WAVES = 4;

typedef __attribute__((ext_vector_type(8))) short bf16x8;
typedef __attribute__((ext_vector_type(4))) float f32x4;

#define RCPF(x) __builtin_amdgcn_rcpf(x)
#define EXP2F(x) __builtin_amdgcn_exp2f(x)

__device__ __forceinline__ unsigned short bf16_rne(float f) {
    unsigned u = __float_as_uint(f);
    unsigned r = u + 0x7FFFu + ((u >> 16) & 1u);
    return (unsigned short)(r >> 16);
}
__device__ __forceinline__ float bf16_f(unsigned short h) {
    return __uint_as_float(((unsigned)h) << 16);
}
__device__ __forceinline__ void split3(float x, unsigned short& h0,
                                       unsigned short& h1, unsigned short& h2) {
    h0 = bf16_rne(x);
    float r = x - bf16_f(h0);
    h1 = bf16_rne(r);
    h2 = bf16_rne(r - bf16_f(h1));
}

// split a pair of fp32 into 3 packed-bf16 words via HW cvt (RNE)
__device__ __forceinline__ void split_pair(float a, float b, unsigned& p0,
                                           unsigned& p1, unsigned& p2) {
    asm("v_cvt_pk_bf16_f32 %0, %1, %2" : "=v"(p0) : "v"(a), "v"(b));
    float ra = a - __uint_as_float(p0 << 16);
    float rb = b - __uint_as_float(p0 & 0xFFFF0000u);
    asm("v_cvt_pk_bf16_f32 %0, %1, %2" : "=v"(p1) : "v"(ra), "v"(rb));
    float ra2 = ra - __uint_as_float(p1 << 16);
    float rb2 = rb - __uint_as_float(p1 & 0xFFFF0000u);
    asm("v_cvt_pk_bf16_f32 %0, %1, %2" : "=v"(p2) : "v"(ra2), "v"(rb2));
}

// gelu: a * (0.5 + 0.5*erf(a/sqrt2)), A&S 7.1.26 erf (validated R2-R10)
__device__ __forceinline__ float fast_gelu(float a) {
    const float p  = 0.3275911f;
    const float c1 = 0.254829592f, c2 = -0.284496736f, c3 = 1.421413741f,
                c4 = -1.453152027f, c5 = 1.061405429f;
    float az = fabsf(a) * 0.70710678118654752f;
    float t  = RCPF(fmaf(p, az, 1.0f));
    float poly = fmaf(fmaf(fmaf(fmaf(c5, t, c4), t, c3), t, c2), t, c1) * t;
    float ez = EXP2F(az * az * -1.4426950408889634f);
    float e  = fmaf(-poly, ez, 1.0f);
    float es = copysignf(e, a);
    return a * fmaf(es, 0.5f, 0.5f);
}

// fp64 ln(x), x in (1e-10, 64), rel err ~1e-13 (validated R4-R10)
__device__ __forceinline__ double fast_log(double x) {
    long long bits = __double_as_longlong(x);
    int e = (int)(bits >> 52) - 1023;
    double m = __longlong_as_double((bits & 0x000FFFFFFFFFFFFFLL) |
                                    0x3FF0000000000000LL);
    if (m > 1.4142135623730951) { m *= 0.5; e += 1; }
    double num = m - 1.0, den = m + 1.0;
    double r = (double)RCPF((float)den);
    r = r * (2.0 - den * r);
    r = r * (2.0 - den * r);
    double s = num * r, s2 = s * s;
    double q = fma(s2, 1.0 / 15.0, 1.0 / 13.0);
    q = fma(s2, q, 1.0 / 11.0);
    q = fma(s2, q, 1.0 / 9.0);
    q = fma(s2, q, 1.0 / 7.0);
    q = fma(s2, q, 1.0 / 5.0);
    q = fma(s2, q, 1.0 / 3.0);
    q = fma(s2, q, 1.0);
    return fma((double)e, 0.6931471805599453, (s + s) * q);
}

// 16-lane-group sum via DPP butterfly (validated R9/R10)
__device__ __forceinline__ float dpp_reduce16(float p) {
    p += __int_as_float(__builtin_amdgcn_update_dpp(
        0, __float_as_int(p), 0xB1, 0xF, 0xF, true));
    p += __int_as_float(__builtin_amdgcn_update_dpp(
        0, __float_as_int(p), 0x4E, 0xF, 0xF, true));
    p += __int_as_float(__builtin_amdgcn_update_dpp(
        0, __float_as_int(p), 0x141, 0xF, 0xF, true));
    p += __int_as_float(__builtin_amdgcn_update_dpp(
        0, __float_as_int(p), 0x140, 0xF, 0xF, true));
    return p;
}

__global__ __launch_bounds__(256, 4) void router_kernel(
    const float* __restrict__ ctx, const float* __restrict__ u,
    const float* __restrict__ tw1, const float* __restrict__ tb1,
    const float* __restrict__ tw2, const float* __restrict__ tb2,
    const float* __restrict__ cw1, const float* __restrict__ cb1,
    const float* __restrict__ cw2, const float* __restrict__ cb2,
    float* __restrict__ out)
{
    __shared__ uint4 Bsh[3][4][64];            // B-frags: split x ct x lane, 12 KB
    __shared__ float tv[WAVES][64 * Cn];       // per-wave t values, 13.3 KB

    const int tid = threadIdx.x;
    const int wid = tid >> 6;
    const int l = tid & 63;
    const long bw = (long)blockIdx.x * 256 + wid * 64;   // wave owns 64 b
    const int col = l & 15;                    // MFMA col / A row in tile
    const int kgrp = l >> 4;                   // k-group 0..3
    const int koff = (kgrp < 3 ? kgrp : 2) * 8;  // kgrp3 dups kgrp2 (B=0)

    // ---- build shared B-fragments: thread tid -> (ct = tid>>6, lane = tid&63)
    {
        const int bct = tid >> 6, bl = tid & 63;
        const int bcol = bl & 15, bkg = bl >> 4;
        const int h = bct * 16 + bcol;
        union { unsigned w[4]; uint4 q; } q0, q1, q2;
        #pragma unroll
        for (int jj = 0; jj < 4; ++jj) {
            unsigned short a0, a1, a2, b0, b1, b2;
            int k0 = bkg * 8 + 2 * jj, k1 = k0 + 1;
            float wa = (k0 < Tn) ? tw1[k0 * Hn + h] : 0.0f;
            float wb = (k1 < Tn) ? tw1[k1 * Hn + h] : 0.0f;
            split3(wa, a0, a1, a2);
            split3(wb, b0, b1, b2);
            q0.w[jj] = (unsigned)a0 | ((unsigned)b0 << 16);
            q1.w[jj] = (unsigned)a1 | ((unsigned)b1 << 16);
            q2.w[jj] = (unsigned)a2 | ((unsigned)b2 << 16);
        }
        Bsh[0][bct][bl] = q0.q;
        Bsh[1][bct][bl] = q1.q;
        Bsh[2][bct][bl] = q2.q;
    }

    // per-lane fc2 weights / fc1 bias (8 regs)
    float w2v[4], biasv[4];
    #pragma unroll
    for (int ct = 0; ct < 4; ++ct) {
        w2v[ct] = tw2[ct * 16 + col];
        biasv[ct] = tb1[ct * 16 + col];
    }
    const float tb2v = tb2[0];

    __syncthreads();

    // ====== phase 1: fc1 via MFMA (LDS B-frags) + gelu + fc2 ======
    const long rowBase = bw * Cn;              // 832 rows per wave
    const float* xr0 = ctx + (rowBase + col) * (long)Tn + koff;
    float4 xa = *reinterpret_cast<const float4*>(xr0);
    float4 xb = *reinterpret_cast<const float4*>(xr0 + 4);

    #pragma unroll 1
    for (int it = 0; it < 52; ++it) {          // it = si*2 + tt (16 rows each)
        // prefetch next 16-row tile's x
        const int nit = (it < 51) ? it + 1 : 51;
        const float* xrn =
            ctx + (rowBase + nit * 16 + col) * (long)Tn + koff;
        float4 na = *reinterpret_cast<const float4*>(xrn);
        float4 nb = *reinterpret_cast<const float4*>(xrn + 4);

        union { unsigned w[4]; bf16x8 v; } F0, F1, F2;
        split_pair(xa.x, xa.y, F0.w[0], F1.w[0], F2.w[0]);
        split_pair(xa.z, xa.w, F0.w[1], F1.w[1], F2.w[1]);
        split_pair(xb.x, xb.y, F0.w[2], F1.w[2], F2.w[2]);
        split_pair(xb.z, xb.w, F0.w[3], F1.w[3], F2.w[3]);
        bf16x8 Af0 = F0.v, Af1 = F1.v, Af2 = F2.v;

        float p0 = 0.0f, p1 = 0.0f, p2 = 0.0f, p3 = 0.0f;
        #pragma unroll
        for (int ct = 0; ct < 4; ++ct) {
            union { uint4 q; bf16x8 v; } B0, B1, B2;
            B0.q = Bsh[0][ct][l];
            B1.q = Bsh[1][ct][l];
            B2.q = Bsh[2][ct][l];
            f32x4 acc = (f32x4){ biasv[ct], biasv[ct], biasv[ct], biasv[ct] };
            acc = __builtin_amdgcn_mfma_f32_16x16x32_bf16(Af0, B0.v, acc, 0, 0, 0);
            acc = __builtin_amdgcn_mfma_f32_16x16x32_bf16(Af0, B1.v, acc, 0, 0, 0);
            acc = __builtin_amdgcn_mfma_f32_16x16x32_bf16(Af1, B0.v, acc, 0, 0, 0);
            acc = __builtin_amdgcn_mfma_f32_16x16x32_bf16(Af1, B1.v, acc, 0, 0, 0);
            acc = __builtin_amdgcn_mfma_f32_16x16x32_bf16(Af0, B2.v, acc, 0, 0, 0);
            acc = __builtin_amdgcn_mfma_f32_16x16x32_bf16(Af2, B0.v, acc, 0, 0, 0);

            p0 = fmaf(fast_gelu(acc[0]), w2v[ct], p0);
            p1 = fmaf(fast_gelu(acc[1]), w2v[ct], p1);
            p2 = fmaf(fast_gelu(acc[2]), w2v[ct], p2);
            p3 = fmaf(fast_gelu(acc[3]), w2v[ct], p3);
        }

        p0 = dpp_reduce16(p0);
        p1 = dpp_reduce16(p1);
        p2 = dpp_reduce16(p2);
        p3 = dpp_reduce16(p3);
        if (col < 4) {   // 16 writer lanes -> 16 rows of this tile
            float val = (col & 1) ? ((col & 2) ? p3 : p1)
                                  : ((col & 2) ? p2 : p0);
            tv[wid][it * 16 + kgrp * 4 + col] = val + tb2v;
        }
        xa = na; xb = nb;
    }

    __syncthreads();   // cross-lane tv handoff

    // ================= phase 2: per-b c_mlp + gumbel + softmax + topk =======
    const long b = bw + l;

    float t13[Cn];
    #pragma unroll
    for (int c = 0; c < Cn; ++c) t13[c] = tv[wid][l * Cn + c];

    float logits[En];
    #pragma unroll
    for (int e = 0; e < En; ++e) logits[e] = cb2[e];

    #pragma unroll 1
    for (int h = 0; h < Hn; ++h) {
        float a = cb1[h];
        #pragma unroll
        for (int c = 0; c < Cn; ++c)
            a = fmaf(t13[c], cw1[c * Hn + h], a);
        float gg = fast_gelu(a);
        #pragma unroll
        for (int e = 0; e < En; ++e)
            logits[e] = fmaf(gg, cw2[h * En + e], logits[e]);
    }

    // gumbel (custom fp64 logs), y = logits + g; unroll 2 caps fp64 pressure
    const float4* up = reinterpret_cast<const float4*>(u + b * En);
    float4 u0 = up[0], u1 = up[1];
    float uv[En] = { u0.x, u0.y, u0.z, u0.w, u1.x, u1.y, u1.z, u1.w };

    double y[En];
    #pragma unroll 2
    for (int e = 0; e < En; ++e) {
        double w = -fast_log((double)uv[e]);
        y[e] = (double)logits[e] - fast_log(w + 1e-10);   // tau = 1
    }

    // softmax in fp32 (probs compared at bf16 tolerance)
    double m = y[0];
    #pragma unroll
    for (int e = 1; e < En; ++e) m = fmax(m, y[e]);
    float p[En], s = 0.0f;
    #pragma unroll
    for (int e = 0; e < En; ++e) {
        p[e] = EXP2F((float)(y[e] - m) * 1.4426950408889634f);
        s += p[e];
    }
    float inv = RCPF(s);

    // top-3 on y (fp64 ordering == probs ordering), bitmask
    unsigned sel = 0u;
    #pragma unroll
    for (int k = 0; k < Kn; ++k) {
        int best = 0;
        double bv = -1.0e300;
        #pragma unroll
        for (int e = 0; e < En; ++e) {
            bool ok = (((sel >> e) & 1u) == 0u) && (y[e] > bv);
            bv = ok ? y[e] : bv;
            best = ok ? e : best;
        }
        sel |= (1u << best);
    }

    // stores
    float4* om = reinterpret_cast<float4*>(out + b * En);
    om[0] = make_float4((sel >> 0) & 1u, (sel >> 1) & 1u,
                        (sel >> 2) & 1u, (sel >> 3) & 1u);
    om[1] = make_float4((sel >> 4) & 1u, (sel >> 5) & 1u,
                        (sel >> 6) & 1u, (sel >> 7) & 1u);
    float4* op = reinterpret_cast<float4*>(out + (long)Bn * En + b * En);
    op[0] = make_float4(p[0] * inv, p[1] * inv, p[2] * inv, p[3] * inv);
    op[1] = make_float4(p[4] * inv, p[5] * inv, p[6] * inv, p[7] * inv);
}

extern "C" void kernel_launch(void* const* d_in, const int* in_sizes, int n_in,
                              void* d_out, int out_size, void* d_ws, size_t ws_size,
                              hipStream_t stream) {
    const float* ctx = (const float*)d_in[0];
    const float* u   = (const float*)d_in[1];
    const float* tw1 = (const float*)d_in[2];
    const float* tb1 = (const float*)d_in[3];
    const float* tw2 = (const float*)d_in[4];
    const float* tb2 = (const float*)d_in[5];
    const float* cw1 = (const float*)d_in[6];
    const float* cb1 = (const float*)d_in[7];
    const float* cw2 = (const float*)d_in[8];
    const float* cb2 = (const float*)d_in[9];
    float* out = (float*)d_out;

    dim3 grid(Bn / 256), block(256);
    router_kernel<<<grid, block, 0, stream>>>(ctx, u, tw1, tb1, tw2, tb2,
                                              cw1, cb1, cw2, cb2, out);
}

// Round 12
// 358.141 us; speedup vs baseline: 1.0526x; 1.0526x over previous
//
#include <hip/hip_runtime.h>
#include <math.h>

// EnvAwareRouter: B=524288, C=13, T=24, H=64, E=8, K=3, tau=1, eps=1e-10
// Output: concat[ mask(B,E), probs(B,E) ] f32
//
// R12: latency-bound diagnosis (true VALUBusy ~25-30%; derived counters are
// gfx94x-formula-inflated 3-4x; static work is ~130us vs 377us measured).
//  - B-fragments in registers (48 VGPR, built once): kills R11's per-tile
//    ds_read -> MFMA latency chains (VGPR=40 proved no LICM hoist).
//  - manual 2-stage software pipeline: split tile it+1's x while tile it's
//    MFMAs are in flight; x loads issued 2 tiles ahead.
//  - __launch_bounds__(256,4): 128-reg cap fits the ~115-reg steady state.
//  - numerics verbatim R10/R11 (validated absmax 0.0039): bf16x3 MFMA
//    6 products, A&S erf gelu, custom fp64 gumbel log, fp64 y ordering.

constexpr int Bn = 524288, Cn = 13, Tn = 24, Hn = 64, En = 8, Kn = 3;
constexpr int WAVES = 4;

typedef __attribute__((ext_vector_type(8))) short bf16x8;
typedef __attribute__((ext_vector_type(4))) float f32x4;

#define RCPF(x) __builtin_amdgcn_rcpf(x)
#define EXP2F(x) __builtin_amdgcn_exp2f(x)

__device__ __forceinline__ unsigned short bf16_rne(float f) {
    unsigned u = __float_as_uint(f);
    unsigned r = u + 0x7FFFu + ((u >> 16) & 1u);
    return (unsigned short)(r >> 16);
}
__device__ __forceinline__ float bf16_f(unsigned short h) {
    return __uint_as_float(((unsigned)h) << 16);
}
__device__ __forceinline__ void split3(float x, unsigned short& h0,
                                       unsigned short& h1, unsigned short& h2) {
    h0 = bf16_rne(x);
    float r = x - bf16_f(h0);
    h1 = bf16_rne(r);
    h2 = bf16_rne(r - bf16_f(h1));
}

// split a pair of fp32 into 3 packed-bf16 words via HW cvt (RNE)
__device__ __forceinline__ void split_pair(float a, float b, unsigned& p0,
                                           unsigned& p1, unsigned& p2) {
    asm("v_cvt_pk_bf16_f32 %0, %1, %2" : "=v"(p0) : "v"(a), "v"(b));
    float ra = a - __uint_as_float(p0 << 16);
    float rb = b - __uint_as_float(p0 & 0xFFFF0000u);
    asm("v_cvt_pk_bf16_f32 %0, %1, %2" : "=v"(p1) : "v"(ra), "v"(rb));
    float ra2 = ra - __uint_as_float(p1 << 16);
    float rb2 = rb - __uint_as_float(p1 & 0xFFFF0000u);
    asm("v_cvt_pk_bf16_f32 %0, %1, %2" : "=v"(p2) : "v"(ra2), "v"(rb2));
}

// gelu: a * (0.5 + 0.5*erf(a/sqrt2)), A&S 7.1.26 erf (validated R2-R11)
__device__ __forceinline__ float fast_gelu(float a) {
    const float p  = 0.3275911f;
    const float c1 = 0.254829592f, c2 = -0.284496736f, c3 = 1.421413741f,
                c4 = -1.453152027f, c5 = 1.061405429f;
    float az = fabsf(a) * 0.70710678118654752f;
    float t  = RCPF(fmaf(p, az, 1.0f));
    float poly = fmaf(fmaf(fmaf(fmaf(c5, t, c4), t, c3), t, c2), t, c1) * t;
    float ez = EXP2F(az * az * -1.4426950408889634f);
    float e  = fmaf(-poly, ez, 1.0f);
    float es = copysignf(e, a);
    return a * fmaf(es, 0.5f, 0.5f);
}

// fp64 ln(x), x in (1e-10, 64), rel err ~1e-13 (validated R4-R11)
__device__ __forceinline__ double fast_log(double x) {
    long long bits = __double_as_longlong(x);
    int e = (int)(bits >> 52) - 1023;
    double m = __longlong_as_double((bits & 0x000FFFFFFFFFFFFFLL) |
                                    0x3FF0000000000000LL);
    if (m > 1.4142135623730951) { m *= 0.5; e += 1; }
    double num = m - 1.0, den = m + 1.0;
    double r = (double)RCPF((float)den);
    r = r * (2.0 - den * r);
    r = r * (2.0 - den * r);
    double s = num * r, s2 = s * s;
    double q = fma(s2, 1.0 / 15.0, 1.0 / 13.0);
    q = fma(s2, q, 1.0 / 11.0);
    q = fma(s2, q, 1.0 / 9.0);
    q = fma(s2, q, 1.0 / 7.0);
    q = fma(s2, q, 1.0 / 5.0);
    q = fma(s2, q, 1.0 / 3.0);
    q = fma(s2, q, 1.0);
    return fma((double)e, 0.6931471805599453, (s + s) * q);
}

// 16-lane-group sum via DPP butterfly (validated R9-R11)
__device__ __forceinline__ float dpp_reduce16(float p) {
    p += __int_as_float(__builtin_amdgcn_update_dpp(
        0, __float_as_int(p), 0xB1, 0xF, 0xF, true));
    p += __int_as_float(__builtin_amdgcn_update_dpp(
        0, __float_as_int(p), 0x4E, 0xF, 0xF, true));
    p += __int_as_float(__builtin_amdgcn_update_dpp(
        0, __float_as_int(p), 0x141, 0xF, 0xF, true));
    p += __int_as_float(__builtin_amdgcn_update_dpp(
        0, __float_as_int(p), 0x140, 0xF, 0xF, true));
    return p;
}

__global__ __launch_bounds__(256, 4) void router_kernel(
    const float* __restrict__ ctx, const float* __restrict__ u,
    const float* __restrict__ tw1, const float* __restrict__ tb1,
    const float* __restrict__ tw2, const float* __restrict__ tb2,
    const float* __restrict__ cw1, const float* __restrict__ cb1,
    const float* __restrict__ cw2, const float* __restrict__ cb2,
    float* __restrict__ out)
{
    __shared__ float tv[WAVES][64 * Cn];       // per-wave t values, 13.3 KB

    const int tid = threadIdx.x;
    const int wid = tid >> 6;
    const int l = tid & 63;
    const long bw = (long)blockIdx.x * 256 + wid * 64;   // wave owns 64 b
    const int col = l & 15;                    // MFMA col / A row in tile
    const int kgrp = l >> 4;                   // k-group 0..3
    const int koff = (kgrp < 3 ? kgrp : 2) * 8;  // kgrp3 dups kgrp2 (B=0)

    // ---- wave-stationary B-fragments (48 VGPR), fc2/bias regs ----
    bf16x8 B00, B01, B02, B03;   // split 0, ct 0..3
    bf16x8 B10, B11, B12, B13;   // split 1
    bf16x8 B20, B21, B22, B23;   // split 2
    float w2v[4], biasv[4];
    {
        bf16x8* Bs0[4] = { &B00, &B01, &B02, &B03 };
        bf16x8* Bs1[4] = { &B10, &B11, &B12, &B13 };
        bf16x8* Bs2[4] = { &B20, &B21, &B22, &B23 };
        #pragma unroll
        for (int ct = 0; ct < 4; ++ct) {
            const int h = ct * 16 + col;
            w2v[ct] = tw2[h];
            biasv[ct] = tb1[h];
            #pragma unroll
            for (int j = 0; j < 8; ++j) {
                const int k = kgrp * 8 + j;
                float w = (k < Tn) ? tw1[k * Hn + h] : 0.0f;  // K-pad: zero B
                unsigned short w0, w1, w2s;
                split3(w, w0, w1, w2s);
                (*Bs0[ct])[j] = (short)w0;
                (*Bs1[ct])[j] = (short)w1;
                (*Bs2[ct])[j] = (short)w2s;
            }
        }
    }
    const float tb2v = tb2[0];

    // ====== phase 1: software-pipelined MFMA fc1 + gelu + fc2 ======
    const long rowBase = bw * Cn;              // 832 rows per wave

    // preloop: split tile 0, prefetch tile 1
    bf16x8 C0, C1, C2;                         // current tile A-frags
    {
        const float* xr = ctx + (rowBase + col) * (long)Tn + koff;
        float4 xa = *reinterpret_cast<const float4*>(xr);
        float4 xb = *reinterpret_cast<const float4*>(xr + 4);
        union { unsigned w[4]; bf16x8 v; } F0, F1, F2;
        split_pair(xa.x, xa.y, F0.w[0], F1.w[0], F2.w[0]);
        split_pair(xa.z, xa.w, F0.w[1], F1.w[1], F2.w[1]);
        split_pair(xb.x, xb.y, F0.w[2], F1.w[2], F2.w[2]);
        split_pair(xb.z, xb.w, F0.w[3], F1.w[3], F2.w[3]);
        C0 = F0.v; C1 = F1.v; C2 = F2.v;
    }
    const float* xr1 = ctx + (rowBase + 16 + col) * (long)Tn + koff;
    float4 na = *reinterpret_cast<const float4*>(xr1);
    float4 nb = *reinterpret_cast<const float4*>(xr1 + 4);

    #pragma unroll 1
    for (int it = 0; it < 52; ++it) {
        // issue load for tile it+2 (2-deep prefetch)
        const int pit = (it < 50) ? it + 2 : 51;
        const float* xrp = ctx + (rowBase + pit * 16 + col) * (long)Tn + koff;
        float4 la = *reinterpret_cast<const float4*>(xrp);
        float4 lb = *reinterpret_cast<const float4*>(xrp + 4);

        // MFMA chains for current tile (4 independent ct chains)
        f32x4 a0 = (f32x4){ biasv[0], biasv[0], biasv[0], biasv[0] };
        f32x4 a1 = (f32x4){ biasv[1], biasv[1], biasv[1], biasv[1] };
        f32x4 a2 = (f32x4){ biasv[2], biasv[2], biasv[2], biasv[2] };
        f32x4 a3 = (f32x4){ biasv[3], biasv[3], biasv[3], biasv[3] };
        a0 = __builtin_amdgcn_mfma_f32_16x16x32_bf16(C0, B00, a0, 0, 0, 0);
        a1 = __builtin_amdgcn_mfma_f32_16x16x32_bf16(C0, B01, a1, 0, 0, 0);
        a2 = __builtin_amdgcn_mfma_f32_16x16x32_bf16(C0, B02, a2, 0, 0, 0);
        a3 = __builtin_amdgcn_mfma_f32_16x16x32_bf16(C0, B03, a3, 0, 0, 0);
        a0 = __builtin_amdgcn_mfma_f32_16x16x32_bf16(C1, B00, a0, 0, 0, 0);
        a1 = __builtin_amdgcn_mfma_f32_16x16x32_bf16(C1, B01, a1, 0, 0, 0);
        a2 = __builtin_amdgcn_mfma_f32_16x16x32_bf16(C1, B02, a2, 0, 0, 0);
        a3 = __builtin_amdgcn_mfma_f32_16x16x32_bf16(C1, B03, a3, 0, 0, 0);
        a0 = __builtin_amdgcn_mfma_f32_16x16x32_bf16(C0, B10, a0, 0, 0, 0);
        a1 = __builtin_amdgcn_mfma_f32_16x16x32_bf16(C0, B11, a1, 0, 0, 0);
        a2 = __builtin_amdgcn_mfma_f32_16x16x32_bf16(C0, B12, a2, 0, 0, 0);
        a3 = __builtin_amdgcn_mfma_f32_16x16x32_bf16(C0, B13, a3, 0, 0, 0);
        a0 = __builtin_amdgcn_mfma_f32_16x16x32_bf16(C1, B10, a0, 0, 0, 0);
        a1 = __builtin_amdgcn_mfma_f32_16x16x32_bf16(C1, B11, a1, 0, 0, 0);
        a2 = __builtin_amdgcn_mfma_f32_16x16x32_bf16(C1, B12, a2, 0, 0, 0);
        a3 = __builtin_amdgcn_mfma_f32_16x16x32_bf16(C1, B13, a3, 0, 0, 0);
        a0 = __builtin_amdgcn_mfma_f32_16x16x32_bf16(C0, B20, a0, 0, 0, 0);
        a1 = __builtin_amdgcn_mfma_f32_16x16x32_bf16(C0, B21, a1, 0, 0, 0);
        a2 = __builtin_amdgcn_mfma_f32_16x16x32_bf16(C0, B22, a2, 0, 0, 0);
        a3 = __builtin_amdgcn_mfma_f32_16x16x32_bf16(C0, B23, a3, 0, 0, 0);
        a0 = __builtin_amdgcn_mfma_f32_16x16x32_bf16(C2, B00, a0, 0, 0, 0);
        a1 = __builtin_amdgcn_mfma_f32_16x16x32_bf16(C2, B01, a1, 0, 0, 0);
        a2 = __builtin_amdgcn_mfma_f32_16x16x32_bf16(C2, B02, a2, 0, 0, 0);
        a3 = __builtin_amdgcn_mfma_f32_16x16x32_bf16(C2, B03, a3, 0, 0, 0);

        // split NEXT tile's x while MFMAs are in flight (independent VALU)
        union { unsigned w[4]; bf16x8 v; } N0, N1, N2;
        split_pair(na.x, na.y, N0.w[0], N1.w[0], N2.w[0]);
        split_pair(na.z, na.w, N0.w[1], N1.w[1], N2.w[1]);
        split_pair(nb.x, nb.y, N0.w[2], N1.w[2], N2.w[2]);
        split_pair(nb.z, nb.w, N0.w[3], N1.w[3], N2.w[3]);

        // gelu + fc2 partials (C/D: col=l&15, row=kgrp*4+reg)
        float p0 = 0.0f, p1 = 0.0f, p2 = 0.0f, p3 = 0.0f;
        p0 = fmaf(fast_gelu(a0[0]), w2v[0], p0);
        p1 = fmaf(fast_gelu(a0[1]), w2v[0], p1);
        p2 = fmaf(fast_gelu(a0[2]), w2v[0], p2);
        p3 = fmaf(fast_gelu(a0[3]), w2v[0], p3);
        p0 = fmaf(fast_gelu(a1[0]), w2v[1], p0);
        p1 = fmaf(fast_gelu(a1[1]), w2v[1], p1);
        p2 = fmaf(fast_gelu(a1[2]), w2v[1], p2);
        p3 = fmaf(fast_gelu(a1[3]), w2v[1], p3);
        p0 = fmaf(fast_gelu(a2[0]), w2v[2], p0);
        p1 = fmaf(fast_gelu(a2[1]), w2v[2], p1);
        p2 = fmaf(fast_gelu(a2[2]), w2v[2], p2);
        p3 = fmaf(fast_gelu(a2[3]), w2v[2], p3);
        p0 = fmaf(fast_gelu(a3[0]), w2v[3], p0);
        p1 = fmaf(fast_gelu(a3[1]), w2v[3], p1);
        p2 = fmaf(fast_gelu(a3[2]), w2v[3], p2);
        p3 = fmaf(fast_gelu(a3[3]), w2v[3], p3);

        p0 = dpp_reduce16(p0);
        p1 = dpp_reduce16(p1);
        p2 = dpp_reduce16(p2);
        p3 = dpp_reduce16(p3);
        if (col < 4) {   // 16 writer lanes -> 16 rows of this tile
            float val = (col & 1) ? ((col & 2) ? p3 : p1)
                                  : ((col & 2) ? p2 : p0);
            tv[wid][it * 16 + kgrp * 4 + col] = val + tb2v;
        }

        // rotate pipeline
        C0 = N0.v; C1 = N1.v; C2 = N2.v;
        na = la; nb = lb;
    }

    __syncthreads();   // cross-lane tv handoff

    // ================= phase 2: per-b c_mlp + gumbel + softmax + topk =======
    const long b = bw + l;

    float t13[Cn];
    #pragma unroll
    for (int c = 0; c < Cn; ++c) t13[c] = tv[wid][l * Cn + c];

    float logits[En];
    #pragma unroll
    for (int e = 0; e < En; ++e) logits[e] = cb2[e];

    #pragma unroll 1
    for (int h = 0; h < Hn; ++h) {
        float a = cb1[h];
        #pragma unroll
        for (int c = 0; c < Cn; ++c)
            a = fmaf(t13[c], cw1[c * Hn + h], a);
        float gg = fast_gelu(a);
        #pragma unroll
        for (int e = 0; e < En; ++e)
            logits[e] = fmaf(gg, cw2[h * En + e], logits[e]);
    }

    // gumbel (custom fp64 logs), y = logits + g
    const float4* up = reinterpret_cast<const float4*>(u + b * En);
    float4 u0 = up[0], u1 = up[1];
    float uv[En] = { u0.x, u0.y, u0.z, u0.w, u1.x, u1.y, u1.z, u1.w };

    double y[En];
    #pragma unroll 2
    for (int e = 0; e < En; ++e) {
        double w = -fast_log((double)uv[e]);
        y[e] = (double)logits[e] - fast_log(w + 1e-10);   // tau = 1
    }

    // softmax in fp32 (probs compared at bf16 tolerance)
    double m = y[0];
    #pragma unroll
    for (int e = 1; e < En; ++e) m = fmax(m, y[e]);
    float p[En], s = 0.0f;
    #pragma unroll
    for (int e = 0; e < En; ++e) {
        p[e] = EXP2F((float)(y[e] - m) * 1.4426950408889634f);
        s += p[e];
    }
    float inv = RCPF(s);

    // top-3 on y (fp64 ordering == probs ordering), bitmask
    unsigned sel = 0u;
    #pragma unroll
    for (int k = 0; k < Kn; ++k) {
        int best = 0;
        double bv = -1.0e300;
        #pragma unroll
        for (int e = 0; e < En; ++e) {
            bool ok = (((sel >> e) & 1u) == 0u) && (y[e] > bv);
            bv = ok ? y[e] : bv;
            best = ok ? e : best;
        }
        sel |= (1u << best);
    }

    // stores
    float4* om = reinterpret_cast<float4*>(out + b * En);
    om[0] = make_float4((sel >> 0) & 1u, (sel >> 1) & 1u,
                        (sel >> 2) & 1u, (sel >> 3) & 1u);
    om[1] = make_float4((sel >> 4) & 1u, (sel >> 5) & 1u,
                        (sel >> 6) & 1u, (sel >> 7) & 1u);
    float4* op = reinterpret_cast<float4*>(out + (long)Bn * En + b * En);
    op[0] = make_float4(p[0] * inv, p[1] * inv, p[2] * inv, p[3] * inv);
    op[1] = make_float4(p[4] * inv, p[5] * inv, p[6] * inv, p[7] * inv);
}

extern "C" void kernel_launch(void* const* d_in, const int* in_sizes, int n_in,
                              void* d_out, int out_size, void* d_ws, size_t ws_size,
                              hipStream_t stream) {
    const float* ctx = (const float*)d_in[0];
    const float* u   = (const float*)d_in[1];
    const float* tw1 = (const float*)d_in[2];
    const float* tb1 = (const float*)d_in[3];
    const float* tw2 = (const float*)d_in[4];
    const float* tb2 = (const float*)d_in[5];
    const float* cw1 = (const float*)d_in[6];
    const float* cb1 = (const float*)d_in[7];
    const float* cw2 = (const float*)d_in[8];
    const float* cb2 = (const float*)d_in[9];
    float* out = (float*)d_out;

    dim3 grid(Bn / 256), block(256);
    router_kernel<<<grid, block, 0, stream>>>(ctx, u, tw1, tb1, tw2, tb2,
                                              cw1, cb1, cw2, cb2, out);
}